// Round 2
// baseline (149.191 us; speedup 1.0000x reference)
//
#include <hip/hip_runtime.h>
#include <stdint.h>

typedef __attribute__((ext_vector_type(4))) int int4v;

#define NB 96
#define SS 1024
#define DD 64

// Pack byte0 of four int32s (each holding an int8 value) into one dword.
static __device__ __forceinline__ uint32_t pack4(uint32_t a, uint32_t b,
                                                 uint32_t c, uint32_t d) {
    uint32_t lo = __builtin_amdgcn_perm(b, a, 0x00000400u);  // [a0,b0,x,x]
    uint32_t hi = __builtin_amdgcn_perm(d, c, 0x00000400u);  // [c0,d0,x,x]
    return __builtin_amdgcn_perm(hi, lo, 0x05040100u);       // [a0,b0,c0,d0]
}

// out[b][s][t] = alpha * ( (x-az).(y-bz) )
//             = alpha * ( C - bz*rowsum(x) - az*colsum(y) + 64*az*bz )
// C, rowsum, colsum exact in int32 via mfma_i32_16x16x64_i8.
// Inputs arrive as int32 (harness widens integer dtypes) -> pack to int8.
__global__ __launch_bounds__(256) void bmm_i8zp_kernel(
    const int* __restrict__ X,   // [96][1024][64] int32, values in [-128,127]
    const int* __restrict__ Y,   // [96][64][1024] int32
    const float* __restrict__ azp,
    const float* __restrict__ bzp,
    const float* __restrict__ alp,
    float* __restrict__ out)     // [96][1024][1024] fp32
{
    // Transposed+packed B panel: btile[t][kw] dwords, kw XOR-swizzled per row
    __shared__ uint32_t btile[128 * 16];   // 8 KiB

    const int tid = threadIdx.x;
    const int bid = blockIdx.x;
    const int b   = bid >> 6;
    const int mt  = (bid >> 3) & 7;
    const int nt  = bid & 7;
    const int rowbase = mt * 128;
    const int colbase = nt * 128;

    const int* Xb = X + (size_t)b * (SS * DD);
    const int* Yb = Y + (size_t)b * (DD * SS);

    // ---- stage + pack + transpose B panel (64 k x 128 t) into LDS ----
    {
        const int tw = tid & 31;                       // t-quad index (0..31)
        const int4v* srcBase = (const int4v*)(Yb + colbase) + tw;
        #pragma unroll
        for (int it = 0; it < 2; ++it) {
            const int kw = (tid >> 5) + 8 * it;        // 0..15 (k-quad)
            const int4v* src = srcBase + (size_t)(4 * kw) * (SS / 4);
            int4v r0 = src[0];                         // row 4kw,   t0..t0+3
            int4v r1 = src[SS / 4];                    // row 4kw+1
            int4v r2 = src[2 * (SS / 4)];              // row 4kw+2
            int4v r3 = src[3 * (SS / 4)];              // row 4kw+3
            const int t0 = 4 * tw;
            btile[(t0 + 0) * 16 + (kw ^ ((t0 + 0) & 15))] =
                pack4(r0[0], r1[0], r2[0], r3[0]);
            btile[(t0 + 1) * 16 + (kw ^ ((t0 + 1) & 15))] =
                pack4(r0[1], r1[1], r2[1], r3[1]);
            btile[(t0 + 2) * 16 + (kw ^ ((t0 + 2) & 15))] =
                pack4(r0[2], r1[2], r2[2], r3[2]);
            btile[(t0 + 3) * 16 + (kw ^ ((t0 + 3) & 15))] =
                pack4(r0[3], r1[3], r2[3], r3[3]);
        }
    }
    __syncthreads();

    const int wid  = tid >> 6;      // 4 waves, 2x2 over the 128x128 tile
    const int lane = tid & 63;
    const int wm = wid >> 1, wn = wid & 1;
    const int rr = lane & 15, qq = lane >> 4;

    int4v aF[4], bF[4];
    // A fragments: lane holds A[row = base+rr][k = qq*16 .. +15] packed to i8
    #pragma unroll
    for (int m = 0; m < 4; ++m) {
        const int* arow = Xb + (size_t)(rowbase + wm * 64 + m * 16 + rr) * DD
                             + qq * 16;
        int4v v;
        #pragma unroll
        for (int c = 0; c < 4; ++c) {
            int4v w = *(const int4v*)(arow + 4 * c);
            v[c] = (int)pack4((uint32_t)w[0], (uint32_t)w[1],
                              (uint32_t)w[2], (uint32_t)w[3]);
        }
        aF[m] = v;
    }
    // B fragments: lane holds B[k = qq*16 .. +15][col = base+rr] from LDS
    #pragma unroll
    for (int n = 0; n < 4; ++n) {
        const int t = wn * 64 + n * 16 + rr;
        int4v v;
        #pragma unroll
        for (int c = 0; c < 4; ++c) {
            const int kw = qq * 4 + c;
            v[c] = (int)btile[t * 16 + (kw ^ (t & 15))];
        }
        bF[n] = v;
    }

    const int4v ones = {0x01010101, 0x01010101, 0x01010101, 0x01010101};
    const int4v zero = {0, 0, 0, 0};
    int4v rxD[4], cyD[4], acc[4][4];
    #pragma unroll
    for (int m = 0; m < 4; ++m)   // D[r][c] = rowsum(x)[r]
        rxD[m] = __builtin_amdgcn_mfma_i32_16x16x64_i8(aF[m], ones, zero, 0, 0, 0);
    #pragma unroll
    for (int n = 0; n < 4; ++n)   // D[r][c] = colsum(y)[c]
        cyD[n] = __builtin_amdgcn_mfma_i32_16x16x64_i8(ones, bF[n], zero, 0, 0, 0);
    #pragma unroll
    for (int m = 0; m < 4; ++m) {
        #pragma unroll
        for (int n = 0; n < 4; ++n)
            acc[m][n] = __builtin_amdgcn_mfma_i32_16x16x64_i8(aF[m], bF[n], zero, 0, 0, 0);
    }

    const float az = *azp, bz = *bzp, al = *alp;
    const float czk = az * bz * (float)DD;

    float* outb = out + (size_t)b * SS * SS;
    #pragma unroll
    for (int m = 0; m < 4; ++m) {
        #pragma unroll
        for (int j = 0; j < 4; ++j) {
            const int rowg = rowbase + wm * 64 + m * 16 + qq * 4 + j;
            float* orow = outb + (size_t)rowg * SS + colbase + wn * 64 + rr;
            #pragma unroll
            for (int n = 0; n < 4; ++n) {
                float v = ((float)acc[m][n][j]
                           - bz * (float)rxD[m][j]
                           - az * (float)cyD[n][j]
                           + czk) * al;
                orow[n * 16] = v;
            }
        }
    }
}

extern "C" void kernel_launch(void* const* d_in, const int* in_sizes, int n_in,
                              void* d_out, int out_size, void* d_ws, size_t ws_size,
                              hipStream_t stream)
{
    const int* X = (const int*)d_in[0];
    const int* Y = (const int*)d_in[1];
    const float* azp = (const float*)d_in[2];
    const float* bzp = (const float*)d_in[3];
    const float* alp = (const float*)d_in[4];
    float* out = (float*)d_out;

    dim3 grid(NB * 8 * 8);   // 96 batches x 8x8 tiles of 128x128
    dim3 block(256);
    hipLaunchKernelGGL(bmm_i8zp_kernel, grid, block, 0, stream, X, Y, azp, bzp, alp, out);
}

// Round 3
// 97.262 us; speedup vs baseline: 1.5339x; 1.5339x over previous
//
#include <hip/hip_runtime.h>
#include <stdint.h>

typedef __attribute__((ext_vector_type(4))) int int4v;
typedef __attribute__((ext_vector_type(4))) float float4v;

#define NB 96
#define SS 1024
#define DD 64
#define OSTRIDE 132   // 32-row epilogue buffer stride (floats); 132%32=4 -> staggered banks

// Pack byte0 of four int32s (each holding an int8 value) into one dword.
static __device__ __forceinline__ uint32_t pack4(uint32_t a, uint32_t b,
                                                 uint32_t c, uint32_t d) {
    uint32_t lo = __builtin_amdgcn_perm(b, a, 0x00000400u);  // [a0,b0,x,x]
    uint32_t hi = __builtin_amdgcn_perm(d, c, 0x00000400u);  // [c0,d0,x,x]
    return __builtin_amdgcn_perm(hi, lo, 0x05040100u);       // [a0,b0,c0,d0]
}

// out[b][s][t] = alpha * ( C - bz*rowsum(x) - az*colsum(y) + 64*az*bz )
// exact int32 via mfma_i32_16x16x64_i8; inputs arrive widened to int32.
__global__ __launch_bounds__(256) void bmm_i8zp_kernel(
    const int* __restrict__ X,   // [96][1024][64] int32 (int8 values)
    const int* __restrict__ Y,   // [96][64][1024] int32
    const float* __restrict__ azp,
    const float* __restrict__ bzp,
    const float* __restrict__ alp,
    float* __restrict__ out)     // [96][1024][1024] fp32
{
    __shared__ union __align__(16) {
        struct { uint32_t a[128 * 16]; uint32_t b[128 * 16]; } s;  // packed i8 tiles
        float o[32 * OSTRIDE];                                     // epilogue transpose buf
    } u;

    const int tid = threadIdx.x;
    // XCD-aware swizzle: grid 6144 = 8 XCDs x 768; each XCD gets 12 whole batches
    const int bid = (blockIdx.x & 7) * 768 + (blockIdx.x >> 3);
    const int b   = bid >> 6;
    const int mt  = (bid >> 3) & 7;
    const int nt  = bid & 7;
    const int rowbase = mt * 128;
    const int colbase = nt * 128;

    const int* Xb = X + (size_t)b * (SS * DD);
    const int* Yb = Y + (size_t)b * (DD * SS);

    // ---- stage A panel (128 rows x 64 k), pack to i8, swizzled LDS ----
    {
        const int* Xa = Xb + (size_t)rowbase * DD;   // contiguous 32 KB panel
        #pragma unroll
        for (int i = 0; i < 8; ++i) {
            const int g = tid + 256 * i;             // 0..2047 int4v granules
            const int row = g >> 4, kw = g & 15;
            int4v w = *(const int4v*)(Xa + (size_t)g * 4);
            u.s.a[row * 16 + (kw ^ (row & 15))] =
                pack4((uint32_t)w[0], (uint32_t)w[1], (uint32_t)w[2], (uint32_t)w[3]);
        }
    }
    // ---- stage + transpose B panel (64 k x 128 t) ----
    {
        const int tw = tid & 31;
        const int4v* srcBase = (const int4v*)(Yb + colbase) + tw;
        #pragma unroll
        for (int it = 0; it < 2; ++it) {
            const int kw = (tid >> 5) + 8 * it;      // 0..15
            const int4v* src = srcBase + (size_t)(4 * kw) * (SS / 4);
            int4v r0 = src[0];
            int4v r1 = src[SS / 4];
            int4v r2 = src[2 * (SS / 4)];
            int4v r3 = src[3 * (SS / 4)];
            const int t0 = 4 * tw;
            u.s.b[(t0 + 0) * 16 + (kw ^ ((t0 + 0) & 15))] =
                pack4(r0[0], r1[0], r2[0], r3[0]);
            u.s.b[(t0 + 1) * 16 + (kw ^ ((t0 + 1) & 15))] =
                pack4(r0[1], r1[1], r2[1], r3[1]);
            u.s.b[(t0 + 2) * 16 + (kw ^ ((t0 + 2) & 15))] =
                pack4(r0[2], r1[2], r2[2], r3[2]);
            u.s.b[(t0 + 3) * 16 + (kw ^ ((t0 + 3) & 15))] =
                pack4(r0[3], r1[3], r2[3], r3[3]);
        }
    }
    __syncthreads();

    const int wid  = tid >> 6;      // 4 waves, 2x2 over the 128x128 tile
    const int lane = tid & 63;
    const int wm = wid >> 1, wn = wid & 1;
    const int rr = lane & 15, qq = lane >> 4;

    int4v aF[4], bF[4];
    #pragma unroll
    for (int m = 0; m < 4; ++m) {
        const int lr = wm * 64 + m * 16 + rr;
        int4v v;
        #pragma unroll
        for (int c = 0; c < 4; ++c)
            v[c] = (int)u.s.a[lr * 16 + ((qq * 4 + c) ^ (lr & 15))];
        aF[m] = v;
    }
    #pragma unroll
    for (int n = 0; n < 4; ++n) {
        const int t = wn * 64 + n * 16 + rr;
        int4v v;
        #pragma unroll
        for (int c = 0; c < 4; ++c)
            v[c] = (int)u.s.b[t * 16 + ((qq * 4 + c) ^ (t & 15))];
        bF[n] = v;
    }
    __syncthreads();   // staging tiles dead; LDS reused as epilogue buffer

    const int4v ones = {0x01010101, 0x01010101, 0x01010101, 0x01010101};
    const int4v zero = {0, 0, 0, 0};
    int4v cyD[4];
    #pragma unroll
    for (int n = 0; n < 4; ++n)   // colsum(y)[c] in every row slot
        cyD[n] = __builtin_amdgcn_mfma_i32_16x16x64_i8(ones, bF[n], zero, 0, 0, 0);

    const float az = *azp, bz = *bzp, al = *alp;
    const float czk = az * bz * (float)DD;
    float* outb = out + (size_t)b * SS * SS;

    #pragma unroll
    for (int m = 0; m < 4; ++m) {
        int4v rx = __builtin_amdgcn_mfma_i32_16x16x64_i8(aF[m], ones, zero, 0, 0, 0);
        int4v acc[4];
        #pragma unroll
        for (int n = 0; n < 4; ++n)
            acc[n] = __builtin_amdgcn_mfma_i32_16x16x64_i8(aF[m], bF[n], zero, 0, 0, 0);

        // scatter this 32x128 row-chunk (wm halves) into LDS, banks <=2-way
        #pragma unroll
        for (int j = 0; j < 4; ++j) {
            const int lrow = wm * 16 + qq * 4 + j;
            #pragma unroll
            for (int n = 0; n < 4; ++n) {
                const int col = wn * 64 + rr + 16 * n;
                u.o[lrow * OSTRIDE + col] =
                    ((float)acc[n][j] - bz * (float)rx[j]
                     - az * (float)cyD[n][j] + czk) * al;
            }
        }
        __syncthreads();
        // coalesced read-back: each store = 2 full 512B row segments
        const int rbase = rowbase + m * 16;
        #pragma unroll
        for (int i = 0; i < 4; ++i) {
            const int f = tid + 256 * i;          // 0..1023 float4 granules
            const int lrow = f >> 5, c4 = f & 31;
            float4v v = *(const float4v*)&u.o[lrow * OSTRIDE + c4 * 4];
            const int growR = (lrow < 16) ? (rbase + lrow) : (rbase + 48 + lrow);
            *(float4v*)(outb + (size_t)growR * SS + colbase + c4 * 4) = v;
        }
        __syncthreads();
    }
}

extern "C" void kernel_launch(void* const* d_in, const int* in_sizes, int n_in,
                              void* d_out, int out_size, void* d_ws, size_t ws_size,
                              hipStream_t stream)
{
    const int* X = (const int*)d_in[0];
    const int* Y = (const int*)d_in[1];
    const float* azp = (const float*)d_in[2];
    const float* bzp = (const float*)d_in[3];
    const float* alp = (const float*)d_in[4];
    float* out = (float*)d_out;

    dim3 grid(NB * 8 * 8);   // 96 batches x 8x8 tiles of 128x128
    dim3 block(256);
    hipLaunchKernelGGL(bmm_i8zp_kernel, grid, block, 0, stream, X, Y, azp, bzp, alp, out);
}